// Round 14
// baseline (460.939 us; speedup 1.0000x reference)
//
#include <hip/hip_runtime.h>

// Cross product along dim=1 of (16, 3, 1024, 1024) fp32 tensors.
// idx = ((b*3 + c)*1024 + h)*1024 + w; plane = 4MiB; batch = 3 planes.
//
// Measured history (kernel-level):
//  r4  grid-stride all-nt:       122.3us, FETCH 197MB WRITE 197MB, 3.29 TB/s reads CU-side
//  r5  c-split plain loads:      188us, best CU-side delivery 5.35 TB/s
//  r6  contiguous+mixed:         165us REGRESSION (scattered 32KB regions -> row thrash;
//                                lockstep sweep is the right order)
//  r7  4x unroll:                122.1us, VGPR=32 -> loads sunk, experiment void
//  r10 sched_barrier force:      135-139us, VGPR=56 (partial force), occupancy 48->34%
//  => 122us invariant under {nt, grid-stride, phasing, unroll}; worsens with
//     +bytes or broken lockstep. Mix-calibrated fabric ceiling (fill 6.6 W-only,
//     copy 6.29 1:1) puts r4 at ~80% -> floor ~97-105us.
//
// r11: LAST single-variable test. Exact r4 structure; one change: loads are
// plain/cacheable (nt kept on stores only). Theory: nt loads = evict-first +
// slower return path; r5's plain loads posted the best CU-side rate. If flat,
// declare floor.

typedef float vf4 __attribute__((ext_vector_type(4)));

#define P4 (1024 * 1024 / 4)   // float4 elements per component plane (262144, pow2)

#define NTS(v, p) __builtin_nontemporal_store((v), (p))

__device__ __forceinline__ long plane_base(int i) {
    // i in [0, 16*P4): batch = i / P4, r = i % P4
    return (long)(i >> 18) * (3 * P4) + (i & (P4 - 1));
}

__global__ __launch_bounds__(256) void cross_kernel(
    const vf4* __restrict__ a,
    const vf4* __restrict__ b,
    vf4* __restrict__ out,
    int n4)   // total float4 positions = 16 * P4 = 4,194,304
{
    const int nth = gridDim.x * blockDim.x;
    int i = blockIdx.x * blockDim.x + threadIdx.x;

    // Pair-unrolled grid-stride loop, identical to r4 (compiler will schedule
    // as it did there; that config measured 122.3us).
    for (; i + nth < n4; i += 2 * nth) {
        const long p = plane_base(i);
        const long q = plane_base(i + nth);

        vf4 a0 = a[p];
        vf4 a1 = a[p + P4];
        vf4 a2 = a[p + 2 * P4];
        vf4 b0 = b[p];
        vf4 b1 = b[p + P4];
        vf4 b2 = b[p + 2 * P4];

        vf4 a3 = a[q];
        vf4 a4 = a[q + P4];
        vf4 a5 = a[q + 2 * P4];
        vf4 b3 = b[q];
        vf4 b4 = b[q + P4];
        vf4 b5 = b[q + 2 * P4];

        NTS(a1 * b2 - a2 * b1, out + p);
        NTS(a2 * b0 - a0 * b2, out + p + P4);
        NTS(a0 * b1 - a1 * b0, out + p + 2 * P4);

        NTS(a4 * b5 - a5 * b4, out + q);
        NTS(a5 * b3 - a3 * b5, out + q + P4);
        NTS(a3 * b4 - a4 * b3, out + q + 2 * P4);
    }

    // Tail (dead for this shape, kept for safety).
    if (i < n4) {
        const long p = plane_base(i);
        vf4 a0 = a[p], a1 = a[p + P4], a2 = a[p + 2 * P4];
        vf4 b0 = b[p], b1 = b[p + P4], b2 = b[p + 2 * P4];
        NTS(a1 * b2 - a2 * b1, out + p);
        NTS(a2 * b0 - a0 * b2, out + p + P4);
        NTS(a0 * b1 - a1 * b0, out + p + 2 * P4);
    }
}

extern "C" void kernel_launch(void* const* d_in, const int* in_sizes, int n_in,
                              void* d_out, int out_size, void* d_ws, size_t ws_size,
                              hipStream_t stream) {
    const vf4* a = (const vf4*)d_in[0];
    const vf4* b = (const vf4*)d_in[1];
    vf4* out = (vf4*)d_out;

    int n4 = out_size / 3 / 4;   // 4,194,304
    int block = 256;
    // 8 positions per thread -> 2048 blocks (8 blocks/CU), 4 pair-iterations.
    int grid = (n4 + block * 8 - 1) / (block * 8);
    cross_kernel<<<grid, block, 0, stream>>>(a, b, out, n4);
}